// Round 3
// baseline (801.734 us; speedup 1.0000x reference)
//
#include <hip/hip_runtime.h>
#include <hip/hip_bf16.h>

typedef unsigned short u16;
typedef __attribute__((ext_vector_type(8))) __bf16 bf16x8;
typedef __attribute__((ext_vector_type(4))) float f32x4;

__device__ __forceinline__ float bf2f(u16 u) {
    union { unsigned i; float f; } v; v.i = ((unsigned)u) << 16; return v.f;
}
__device__ __forceinline__ u16 f2bf(float f) {
    union { float f; unsigned i; } v; v.f = f;
    unsigned r = (v.i + 0x7FFFu + ((v.i >> 16) & 1u)) >> 16;
    return (u16)r;
}
__device__ __forceinline__ float gelu_f(float x) {
    return 0.5f * x * (1.0f + erff(x * 0.70710678118654752f));
}
// runtime-dtype scalar load: f ? fp32 : bf16
__device__ __forceinline__ float ldx(const void* p, size_t i, int f) {
    return f ? ((const float*)p)[i] : bf2f(((const u16*)p)[i]);
}

// element offsets inside the canonical small-vector buffer (u16)
#define OP_E   0
#define PT_E   2304
#define POS_E  4864
#define CTX_B  6400
#define CTX_G  7424
#define CTX_BE 8448
#define S_B1   9472
#define S_G    9984
#define S_BE   10496
#define S_W2   11008
#define S_B2   12544
#define D_B1   12552
#define D_G    15624
#define D_BE   18696
#define D_B2   21768
#define A_B1   21832
#define A_W2   22344
#define A_B2   22856
#define SMALL_TOTAL 22864

// ---------------------------------------------------------------------------
// dtype detect: bf16 data -> exponents cluster near 127; fp32 read as u16
// pairs -> even words have uniform random exponents (~22% >= 200).
// ---------------------------------------------------------------------------
__global__ __launch_bounds__(256) void detect_dtype(const void* __restrict__ hidden,
                                                    int* __restrict__ flag)
{
    __shared__ int cnt;
    if (threadIdx.x == 0) cnt = 0;
    __syncthreads();
    const u16* h = (const u16*)hidden;
    int c = 0;
    for (int i = threadIdx.x; i < 4096; i += 256) {
        int e = (h[i] >> 7) & 0xFF;
        if (e >= 200) ++c;
    }
    atomicAdd(&cnt, c);
    __syncthreads();
    if (threadIdx.x == 0) *flag = (cnt > 100) ? 1 : 0;
}

// ---------------------------------------------------------------------------
// canonicalize all small vectors to bf16 in one buffer
// ---------------------------------------------------------------------------
struct SmallTab {
    const void* src[18];
    int off[18];
    int cnt[18];
};

__global__ __launch_bounds__(256) void convert_small(SmallTab tab, const int* __restrict__ flag,
                                                     u16* __restrict__ dst)
{
    int idx = blockIdx.x * 256 + threadIdx.x;
    int f = *flag;
#pragma unroll
    for (int e = 0; e < 18; ++e) {
        if (idx < tab.cnt[e]) {
            float v = f ? ((const float*)tab.src[e])[idx]
                        : bf2f(((const u16*)tab.src[e])[idx]);
            dst[tab.off[e] + idx] = f2bf(v);
            return;
        }
        idx -= tab.cnt[e];
    }
}

// ---------------------------------------------------------------------------
// Transpose weights to B^T ([N,K] row-major) bf16.
// z==8: ctx_w rows 0..1023 -> ctxWt ; z==0: sign_w1 ; z==1: aux_w1 ;
// z>=2: dig_w1[p=z-2][:1024] -> BtAll rows (z)*512..
// ---------------------------------------------------------------------------
__global__ __launch_bounds__(256) void transpose_all(
    const void* __restrict__ ctx_w, const void* __restrict__ sign_w1,
    const void* __restrict__ aux_w1, const void* __restrict__ dig_w1,
    u16* __restrict__ ctxWt, u16* __restrict__ BtAll, const int* __restrict__ dflag)
{
    __shared__ u16 tl[32][33];
    int f = *dflag;
    int z = blockIdx.z;
    const void* src; u16* dst; size_t srcOff = 0; int srcLd, cols;
    if (z == 8) { src = ctx_w; dst = ctxWt; srcLd = 1024; cols = 1024; }
    else {
        srcLd = 512; cols = 512;
        if (z == 0) src = sign_w1;
        else if (z == 1) src = aux_w1;
        else { src = dig_w1; srcOff = (size_t)(z - 2) * 1280 * 512; }
        dst = BtAll + (size_t)z * 512 * 1024;
    }
    int n0 = blockIdx.x * 32;
    if (n0 >= cols) return;
    int k0 = blockIdx.y * 32;
    int t = threadIdx.x;
    int r = t >> 3;
    int c4 = (t & 7) * 4;
    size_t si = srcOff + (size_t)(k0 + r) * srcLd + n0 + c4;
    u16 w0, w1, w2, w3;
    if (f) {
        float4 v = *(const float4*)&((const float*)src)[si];
        w0 = f2bf(v.x); w1 = f2bf(v.y); w2 = f2bf(v.z); w3 = f2bf(v.w);
    } else {
        ushort4 v = *(const ushort4*)&((const u16*)src)[si];
        w0 = v.x; w1 = v.y; w2 = v.z; w3 = v.w;
    }
    tl[r][c4 + 0] = w0; tl[r][c4 + 1] = w1; tl[r][c4 + 2] = w2; tl[r][c4 + 3] = w3;
    __syncthreads();
    ushort4 o;
    o.x = tl[c4 + 0][r]; o.y = tl[c4 + 1][r]; o.z = tl[c4 + 2][r]; o.w = tl[c4 + 3][r];
    *(ushort4*)&dst[(size_t)(n0 + r) * 1024 + k0 + c4] = o;
}

// ---------------------------------------------------------------------------
// Row-bias precompute (fp32 out):
//  E_op[b][n]  = op_embed[op[b]] . ctx_w[1024+q][n]
//  P_pt[v][n]  = pt_embed[v]     . ctx_w[1280+q][n]
//  dbias[p][h] = dig_b1[p][h] + pos_embed[p] . dig_w1[p][1024+q][h]
// ---------------------------------------------------------------------------
__global__ __launch_bounds__(256) void precompute_bias(
    const void* __restrict__ ctx_w, const void* __restrict__ dig_w1,
    const u16* __restrict__ csm, const int* __restrict__ op_type,
    const int* __restrict__ dflag,
    float* __restrict__ E_op, float* __restrict__ P_pt, float* __restrict__ dbias)
{
    int f = *dflag;
    int idx = blockIdx.x * 256 + threadIdx.x;
    if (idx < 8192) {
        int b = idx >> 10, n = idx & 1023;
        const u16* e = csm + OP_E + op_type[b] * 256;
        float s = 0.f;
        for (int q = 0; q < 256; ++q)
            s += bf2f(e[q]) * ldx(ctx_w, (size_t)(1024 + q) * 1024 + n, f);
        E_op[idx] = s;
    } else if (idx < 18432) {
        int i = idx - 8192;
        int v = i >> 10, n = i & 1023;
        const u16* e = csm + PT_E + v * 256;
        float s = 0.f;
        for (int q = 0; q < 256; ++q)
            s += bf2f(e[q]) * ldx(ctx_w, (size_t)(1280 + q) * 1024 + n, f);
        P_pt[i] = s;
    } else if (idx < 21504) {
        int i = idx - 18432;
        int p = i >> 9, h = i & 511;
        const u16* e = csm + POS_E + p * 256;
        float s = bf2f(csm[D_B1 + p * 512 + h]);
        for (int q = 0; q < 256; ++q)
            s += bf2f(e[q]) * ldx(dig_w1, (size_t)p * 1280 * 512 + (size_t)(1024 + q) * 512 + h, f);
        dbias[i] = s;
    }
}

// ---------------------------------------------------------------------------
// GEMM: C[M,N] = A[M,K] @ Bt[N,K]^T. A dtype runtime (unless forceB16),
// Bt/C bf16, fp32 accumulate. 128x128 tile, BK=32, 4 waves 2x2, 4x4 accs.
// ---------------------------------------------------------------------------
__global__ __launch_bounds__(256) void gemm_bt(
    const void* __restrict__ Araw, unsigned long long aoff,
    const u16* __restrict__ Bt, u16* __restrict__ C,
    int M, int N, int K, const int* __restrict__ dflag, int forceB16)
{
    __shared__ u16 As[128 * 32];
    __shared__ u16 Bs[128 * 32];
    const int tid = threadIdx.x;
    const int wid = tid >> 6, lane = tid & 63;
    const int m0 = blockIdx.x * 128, n0 = blockIdx.y * 128;
    const int mw = (wid >> 1) * 64, nw = (wid & 1) * 64;
    const int quad = lane >> 4, r16 = lane & 15;
    const int f = forceB16 ? 0 : *dflag;

    const u16* A16 = (const u16*)Araw + aoff;
    const float* A32 = (const float*)Araw + aoff;

    f32x4 acc[4][4] = {};

    const int r0 = tid >> 2;          // 0..63
    const int c8 = (tid & 3) * 8;     // 0,8,16,24

    for (int k0 = 0; k0 < K; k0 += 32) {
        uint4 a0, a1, b0, b1;
        if (f) {
            const float* p0 = &A32[(size_t)(m0 + r0) * K + k0 + c8];
            const float* p1 = &A32[(size_t)(m0 + 64 + r0) * K + k0 + c8];
            float4 x = *(const float4*)p0, y = *(const float4*)(p0 + 4);
            a0.x = f2bf(x.x) | ((unsigned)f2bf(x.y) << 16);
            a0.y = f2bf(x.z) | ((unsigned)f2bf(x.w) << 16);
            a0.z = f2bf(y.x) | ((unsigned)f2bf(y.y) << 16);
            a0.w = f2bf(y.z) | ((unsigned)f2bf(y.w) << 16);
            float4 u = *(const float4*)p1, w = *(const float4*)(p1 + 4);
            a1.x = f2bf(u.x) | ((unsigned)f2bf(u.y) << 16);
            a1.y = f2bf(u.z) | ((unsigned)f2bf(u.w) << 16);
            a1.z = f2bf(w.x) | ((unsigned)f2bf(w.y) << 16);
            a1.w = f2bf(w.z) | ((unsigned)f2bf(w.w) << 16);
        } else {
            a0 = *(const uint4*)&A16[(size_t)(m0 + r0) * K + k0 + c8];
            a1 = *(const uint4*)&A16[(size_t)(m0 + 64 + r0) * K + k0 + c8];
        }
        b0 = *(const uint4*)&Bt[(size_t)(n0 + r0) * K + k0 + c8];
        b1 = *(const uint4*)&Bt[(size_t)(n0 + 64 + r0) * K + k0 + c8];
        __syncthreads();
        *(uint4*)&As[r0 * 32 + c8] = a0;
        *(uint4*)&As[(64 + r0) * 32 + c8] = a1;
        *(uint4*)&Bs[r0 * 32 + c8] = b0;
        *(uint4*)&Bs[(64 + r0) * 32 + c8] = b1;
        __syncthreads();

        bf16x8 af[4], bw[4];
#pragma unroll
        for (int i = 0; i < 4; ++i)
            af[i] = *(const bf16x8*)&As[(mw + i * 16 + r16) * 32 + quad * 8];
#pragma unroll
        for (int j = 0; j < 4; ++j)
            bw[j] = *(const bf16x8*)&Bs[(nw + j * 16 + r16) * 32 + quad * 8];
#pragma unroll
        for (int i = 0; i < 4; ++i)
#pragma unroll
            for (int j = 0; j < 4; ++j)
                acc[i][j] = __builtin_amdgcn_mfma_f32_16x16x32_bf16(
                    af[i], bw[j], acc[i][j], 0, 0, 0);
    }

    // C/D layout: col = lane&15, row = (lane>>4)*4 + reg
#pragma unroll
    for (int i = 0; i < 4; ++i) {
#pragma unroll
        for (int j = 0; j < 4; ++j) {
            int col = n0 + nw + j * 16 + r16;
            size_t base = (size_t)(m0 + mw + i * 16 + quad * 4) * N + col;
#pragma unroll
            for (int r = 0; r < 4; ++r)
                C[base + (size_t)r * N] = f2bf(acc[i][j][r]);
        }
    }
}

// ---------------------------------------------------------------------------
// ctx LN+GELU: context = gelu(LN(ctx_pre + E_op[b] + P_pt[pt] + ctx_b))
// ---------------------------------------------------------------------------
__global__ __launch_bounds__(256) void ln_ctx_kernel(
    const u16* __restrict__ pre, const float* __restrict__ E_op,
    const float* __restrict__ P_pt, const int* __restrict__ ptype,
    const u16* __restrict__ csm, u16* __restrict__ ctx, int tokOff)
{
    __shared__ float red[8];
    int local = blockIdx.x;
    int token = tokOff + local;
    int b = token >> 11;            // T = 2048
    int pt = ptype[token];
    int tid = threadIdx.x;
    int c = tid * 4;
    int wid = tid >> 6, lane = tid & 63;

    ushort4 xp = *(const ushort4*)&pre[(size_t)local * 1024 + c];
    float4 eo = *(const float4*)&E_op[b * 1024 + c];
    float4 pp = *(const float4*)&P_pt[pt * 1024 + c];
    ushort4 cb4 = *(const ushort4*)&csm[CTX_B + c];
    float x[4];
    x[0] = bf2f(xp.x) + eo.x + pp.x + bf2f(cb4.x);
    x[1] = bf2f(xp.y) + eo.y + pp.y + bf2f(cb4.y);
    x[2] = bf2f(xp.z) + eo.z + pp.z + bf2f(cb4.z);
    x[3] = bf2f(xp.w) + eo.w + pp.w + bf2f(cb4.w);

    float s = x[0] + x[1] + x[2] + x[3];
    float s2 = x[0]*x[0] + x[1]*x[1] + x[2]*x[2] + x[3]*x[3];
    for (int off = 32; off; off >>= 1) { s += __shfl_xor(s, off); s2 += __shfl_xor(s2, off); }
    if (lane == 0) { red[wid] = s; red[4 + wid] = s2; }
    __syncthreads();
    s  = red[0] + red[1] + red[2] + red[3];
    s2 = red[4] + red[5] + red[6] + red[7];
    float mean = s * (1.f / 1024.f);
    float var = fmaxf(s2 * (1.f / 1024.f) - mean * mean, 0.f);
    float rs = rsqrtf(var + 1e-5f);

    ushort4 g4 = *(const ushort4*)&csm[CTX_G + c];
    ushort4 b4 = *(const ushort4*)&csm[CTX_BE + c];
    ushort4 o;
    o.x = f2bf(gelu_f((x[0] - mean) * rs * bf2f(g4.x) + bf2f(b4.x)));
    o.y = f2bf(gelu_f((x[1] - mean) * rs * bf2f(g4.y) + bf2f(b4.y)));
    o.z = f2bf(gelu_f((x[2] - mean) * rs * bf2f(g4.z) + bf2f(b4.z)));
    o.w = f2bf(gelu_f((x[3] - mean) * rs * bf2f(g4.w) + bf2f(b4.w)));
    *(ushort4*)&ctx[(size_t)token * 1024 + c] = o;
}

// ---------------------------------------------------------------------------
// sign head finish: LN(512)+GELU then @sign_w2[512,3]+b2. Block per token.
// pre is a [chunk,4096] buffer; cols 0..511.
// ---------------------------------------------------------------------------
__global__ __launch_bounds__(256) void sign_finish(
    const u16* __restrict__ pre, const u16* __restrict__ csm,
    const int* __restrict__ dflag, void* __restrict__ out, int tokOff)
{
    __shared__ float red[8];
    __shared__ float sp[4][3];
    int local = blockIdx.x;
    int tid = threadIdx.x;
    int wid = tid >> 6, lane = tid & 63;
    int c = tid * 2;

    ushort2 xp = *(const ushort2*)&pre[(size_t)local * 4096 + c];
    float x0 = bf2f(xp.x) + bf2f(csm[S_B1 + c]);
    float x1 = bf2f(xp.y) + bf2f(csm[S_B1 + c + 1]);
    float s = x0 + x1, s2 = x0 * x0 + x1 * x1;
    for (int off = 32; off; off >>= 1) { s += __shfl_xor(s, off); s2 += __shfl_xor(s2, off); }
    if (lane == 0) { red[wid] = s; red[4 + wid] = s2; }
    __syncthreads();
    s  = red[0] + red[1] + red[2] + red[3];
    s2 = red[4] + red[5] + red[6] + red[7];
    float mean = s * (1.f / 512.f);
    float var = fmaxf(s2 * (1.f / 512.f) - mean * mean, 0.f);
    float rs = rsqrtf(var + 1e-5f);

    float g0 = gelu_f((x0 - mean) * rs * bf2f(csm[S_G + c]) + bf2f(csm[S_BE + c]));
    float g1 = gelu_f((x1 - mean) * rs * bf2f(csm[S_G + c + 1]) + bf2f(csm[S_BE + c + 1]));
    float p0 = g0 * bf2f(csm[S_W2 + c * 3 + 0]) + g1 * bf2f(csm[S_W2 + (c + 1) * 3 + 0]);
    float p1 = g0 * bf2f(csm[S_W2 + c * 3 + 1]) + g1 * bf2f(csm[S_W2 + (c + 1) * 3 + 1]);
    float p2 = g0 * bf2f(csm[S_W2 + c * 3 + 2]) + g1 * bf2f(csm[S_W2 + (c + 1) * 3 + 2]);
    for (int off = 32; off; off >>= 1) {
        p0 += __shfl_xor(p0, off); p1 += __shfl_xor(p1, off); p2 += __shfl_xor(p2, off);
    }
    if (lane == 0) { sp[wid][0] = p0; sp[wid][1] = p1; sp[wid][2] = p2; }
    __syncthreads();
    if (tid < 3) {
        float v = sp[0][tid] + sp[1][tid] + sp[2][tid] + sp[3][tid] + bf2f(csm[S_B2 + tid]);
        size_t oi = (size_t)(tokOff + local) * 3 + tid;
        if (*dflag) ((float*)out)[oi] = v; else ((u16*)out)[oi] = f2bf(v);
    }
}

// ---------------------------------------------------------------------------
// digit head finish: per (token,p): LN(512)+GELU then h@dig_w2[p]+b2.
// One wave per (token,p); grid (chunk/4, 6); dig_w2[p] staged to LDS.
// pre cols 1024 + p*512.
// ---------------------------------------------------------------------------
__global__ __launch_bounds__(256) void dig_finish(
    const u16* __restrict__ pre, const float* __restrict__ dbias,
    const u16* __restrict__ csm, const void* __restrict__ dw2,
    const int* __restrict__ dflag, void* __restrict__ out, int tokOff)
{
    __shared__ u16 w2s[5120];
    int p = blockIdx.y;
    int f = *dflag;
    if (f) {
        for (int i = threadIdx.x; i < 5120; i += 256)
            w2s[i] = f2bf(((const float*)dw2)[p * 5120 + i]);
    } else {
        for (int i = threadIdx.x; i < 5120; i += 256)
            w2s[i] = ((const u16*)dw2)[p * 5120 + i];
    }
    __syncthreads();

    int wid = threadIdx.x >> 6, lane = threadIdx.x & 63;
    int local = blockIdx.x * 4 + wid;
    const u16* row = pre + (size_t)local * 4096 + 1024 + p * 512 + lane * 8;
    ushort4 a = ((const ushort4*)row)[0];
    ushort4 bq = ((const ushort4*)row)[1];
    u16 xr[8] = {a.x, a.y, a.z, a.w, bq.x, bq.y, bq.z, bq.w};
    int cb = p * 512 + lane * 8;
    float4 d0 = *(const float4*)&dbias[cb];
    float4 d1 = *(const float4*)&dbias[cb + 4];
    float db[8] = {d0.x, d0.y, d0.z, d0.w, d1.x, d1.y, d1.z, d1.w};

    float x[8], s = 0.f, s2 = 0.f;
#pragma unroll
    for (int j = 0; j < 8; ++j) {
        x[j] = bf2f(xr[j]) + db[j];
        s += x[j]; s2 += x[j] * x[j];
    }
    for (int off = 32; off; off >>= 1) { s += __shfl_xor(s, off); s2 += __shfl_xor(s2, off); }
    float mean = s * (1.f / 512.f);
    float var = fmaxf(s2 * (1.f / 512.f) - mean * mean, 0.f);
    float rs = rsqrtf(var + 1e-5f);

    ushort4 g0 = *(const ushort4*)&csm[D_G + cb];
    ushort4 g1 = *(const ushort4*)&csm[D_G + cb + 4];
    ushort4 be0 = *(const ushort4*)&csm[D_BE + cb];
    ushort4 be1 = *(const ushort4*)&csm[D_BE + cb + 4];
    u16 gg[8] = {g0.x, g0.y, g0.z, g0.w, g1.x, g1.y, g1.z, g1.w};
    u16 bb[8] = {be0.x, be0.y, be0.z, be0.w, be1.x, be1.y, be1.z, be1.w};

    float pt[10] = {};
#pragma unroll
    for (int j = 0; j < 8; ++j) {
        float gv = gelu_f((x[j] - mean) * rs * bf2f(gg[j]) + bf2f(bb[j]));
        int wrow = (lane * 8 + j) * 10;
#pragma unroll
        for (int o = 0; o < 10; ++o) pt[o] += gv * bf2f(w2s[wrow + o]);
    }
#pragma unroll
    for (int o = 0; o < 10; ++o)
        for (int off = 32; off; off >>= 1) pt[o] += __shfl_xor(pt[o], off);
    if (lane < 10) {
        float v = pt[lane] + bf2f(csm[D_B2 + p * 10 + lane]);
        size_t oi = 49152 + ((size_t)(tokOff + local) * 6 + p) * 10 + lane;
        if (f) ((float*)out)[oi] = v; else ((u16*)out)[oi] = f2bf(v);
    }
}

// ---------------------------------------------------------------------------
// aux head finish: gelu(pre + b1) . aux_w2 + b2 (no LN). One wave per token.
// pre cols 512..1023.
// ---------------------------------------------------------------------------
__global__ __launch_bounds__(256) void aux_finish(
    const u16* __restrict__ pre, const u16* __restrict__ csm,
    const int* __restrict__ dflag, void* __restrict__ out, int tokOff)
{
    int wid = threadIdx.x >> 6, lane = threadIdx.x & 63;
    int local = blockIdx.x * 4 + wid;
    const u16* row = pre + (size_t)local * 4096 + 512 + lane * 8;
    ushort4 a = ((const ushort4*)row)[0];
    ushort4 bq = ((const ushort4*)row)[1];
    u16 xr[8] = {a.x, a.y, a.z, a.w, bq.x, bq.y, bq.z, bq.w};
    int c = lane * 8;
    float s = 0.f;
#pragma unroll
    for (int j = 0; j < 8; ++j) {
        float xv = bf2f(xr[j]) + bf2f(csm[A_B1 + c + j]);
        s += gelu_f(xv) * bf2f(csm[A_W2 + c + j]);
    }
    for (int off = 32; off; off >>= 1) s += __shfl_xor(s, off);
    if (lane == 0) {
        float v = s + bf2f(csm[A_B2]);
        size_t oi = 1032192 + (size_t)(tokOff + local);
        if (*dflag) ((float*)out)[oi] = v; else ((u16*)out)[oi] = f2bf(v);
    }
}

// ---------------------------------------------------------------------------
extern "C" void kernel_launch(void* const* d_in, const int* in_sizes, int n_in,
                              void* d_out, int out_size, void* d_ws, size_t ws_size,
                              hipStream_t stream) {
    const void* hidden    = d_in[0];
    const int*  op_type   = (const int*)d_in[1];
    const int*  pt_type   = (const int*)d_in[2];
    const void* ctx_w     = d_in[6];
    const void* sign_w1   = d_in[10];
    const void* dig_w1    = d_in[16];
    const void* dig_w2    = d_in[20];
    const void* aux_w1    = d_in[22];

    char* ws = (char*)d_ws;
    // ws layout (bytes), total 60,969,216 (< 64 MB):
    u16*   ctxWt   = (u16*)(ws + 0);           //  2,097,152
    u16*   BtAll   = (u16*)(ws + 2097152);     //  8,388,608  [4096,1024]
    float* E_op    = (float*)(ws + 10485760);  //     32,768
    float* P_pt    = (float*)(ws + 10518528);  //     40,960
    float* dbias   = (float*)(ws + 10559488);  //     12,288
    int*   dflag   = (int*)(ws + 10571776);    //        256
    u16*   csm     = (u16*)(ws + 10572032);    //     65,536  canonical small vecs
    u16*   context = (u16*)(ws + 10637568);    // 33,554,432  [16384,1024]
    u16*   scratch = (u16*)(ws + 44192000);    // 16,777,216  ctx_pre chunks / head chunks

    detect_dtype<<<1, 256, 0, stream>>>(hidden, dflag);

    SmallTab tab;
    const void* srcs[18] = { d_in[3], d_in[4], d_in[5], d_in[7], d_in[8], d_in[9],
                             d_in[11], d_in[12], d_in[13], d_in[14], d_in[15],
                             d_in[17], d_in[18], d_in[19], d_in[21],
                             d_in[23], d_in[24], d_in[25] };
    const int offs[18] = { OP_E, PT_E, POS_E, CTX_B, CTX_G, CTX_BE,
                           S_B1, S_G, S_BE, S_W2, S_B2,
                           D_B1, D_G, D_BE, D_B2, A_B1, A_W2, A_B2 };
    const int cnts[18] = { 2304, 2560, 1536, 1024, 1024, 1024,
                           512, 512, 512, 1536, 3,
                           3072, 3072, 3072, 60, 512, 512, 1 };
    for (int i = 0; i < 18; ++i) { tab.src[i] = srcs[i]; tab.off[i] = offs[i]; tab.cnt[i] = cnts[i]; }
    convert_small<<<90, 256, 0, stream>>>(tab, dflag, csm);

    transpose_all<<<dim3(32, 32, 9), 256, 0, stream>>>(
        ctx_w, sign_w1, aux_w1, dig_w1, ctxWt, BtAll, dflag);
    precompute_bias<<<84, 256, 0, stream>>>(
        ctx_w, dig_w1, csm, op_type, dflag, E_op, P_pt, dbias);

    // context GEMM + LN, 2 chunks of 8192 tokens through scratch
    for (int ci = 0; ci < 2; ++ci) {
        gemm_bt<<<dim3(64, 8), 256, 0, stream>>>(
            hidden, (unsigned long long)ci * 8192 * 1024, ctxWt, scratch,
            8192, 1024, 1024, dflag, 0);
        ln_ctx_kernel<<<8192, 256, 0, stream>>>(
            scratch, E_op, P_pt, pt_type, csm, context, ci * 8192);
    }

    // head GEMM + finishes, 8 chunks of 2048 tokens through scratch
    for (int hi = 0; hi < 8; ++hi) {
        int tokOff = hi * 2048;
        gemm_bt<<<dim3(16, 32), 256, 0, stream>>>(
            context, (unsigned long long)tokOff * 1024, BtAll, scratch,
            2048, 4096, 1024, dflag, 1);
        sign_finish<<<2048, 256, 0, stream>>>(scratch, csm, dflag, d_out, tokOff);
        dig_finish<<<dim3(512, 6), 256, 0, stream>>>(scratch, dbias, csm, dig_w2,
                                                     dflag, d_out, tokOff);
        aux_finish<<<512, 256, 0, stream>>>(scratch, csm, dflag, d_out, tokOff);
    }
}

// Round 4
// 667.594 us; speedup vs baseline: 1.2009x; 1.2009x over previous
//
#include <hip/hip_runtime.h>
#include <hip/hip_bf16.h>

typedef unsigned short u16;
typedef __attribute__((ext_vector_type(8))) __bf16 bf16x8;
typedef __attribute__((ext_vector_type(4))) float f32x4;

typedef __attribute__((address_space(1))) const void GVoid;
typedef __attribute__((address_space(3))) void LVoid;

__device__ __forceinline__ void async_load16(const u16* g, u16* l) {
    __builtin_amdgcn_global_load_lds((GVoid*)g, (LVoid*)l, 16, 0, 0);
}

__device__ __forceinline__ float bf2f(u16 u) {
    union { unsigned i; float f; } v; v.i = ((unsigned)u) << 16; return v.f;
}
__device__ __forceinline__ u16 f2bf(float f) {
    union { float f; unsigned i; } v; v.f = f;
    unsigned r = (v.i + 0x7FFFu + ((v.i >> 16) & 1u)) >> 16;
    return (u16)r;
}
__device__ __forceinline__ float gelu_f(float x) {
    return 0.5f * x * (1.0f + erff(x * 0.70710678118654752f));
}

// element offsets inside the canonical small-vector buffer (u16, bf16 values)
#define OP_E   0
#define PT_E   2304
#define POS_E  4864
#define CTX_B  6400
#define CTX_G  7424
#define CTX_BE 8448
#define S_B1   9472
#define S_G    9984
#define S_BE   10496
#define S_W2   11008
#define S_B2   12544
#define D_G    12552
#define D_BE   15624
#define D_B2   18696
#define A_B1   18756
#define A_W2   19268
#define A_B2   19780

// ---------------------------------------------------------------------------
// canonicalize all small fp32 vectors to bf16 in one buffer
// ---------------------------------------------------------------------------
struct SmallTab {
    const float* src[17];
    int off[17];
    int cnt[17];
};

__global__ __launch_bounds__(256) void convert_small(SmallTab tab, u16* __restrict__ dst)
{
    int idx = blockIdx.x * 256 + threadIdx.x;
#pragma unroll
    for (int e = 0; e < 17; ++e) {
        if (idx < tab.cnt[e]) {
            dst[tab.off[e] + idx] = f2bf(tab.src[e][idx]);
            return;
        }
        idx -= tab.cnt[e];
    }
}

// ---------------------------------------------------------------------------
// Transpose fp32 weights to B^T ([N,K] row-major) bf16.
// z==8: ctx_w rows 0..1023 -> ctxWt ; z==0: sign_w1 ; z==1: aux_w1 ;
// z>=2: dig_w1[p=z-2][:1024] -> BtAll rows z*512..
// ---------------------------------------------------------------------------
__global__ __launch_bounds__(256) void transpose_all(
    const float* __restrict__ ctx_w, const float* __restrict__ sign_w1,
    const float* __restrict__ aux_w1, const float* __restrict__ dig_w1,
    u16* __restrict__ ctxWt, u16* __restrict__ BtAll)
{
    __shared__ u16 tl[32][33];
    int z = blockIdx.z;
    const float* src; u16* dst; size_t srcOff = 0; int srcLd, cols;
    if (z == 8) { src = ctx_w; dst = ctxWt; srcLd = 1024; cols = 1024; }
    else {
        srcLd = 512; cols = 512;
        if (z == 0) src = sign_w1;
        else if (z == 1) src = aux_w1;
        else { src = dig_w1; srcOff = (size_t)(z - 2) * 1280 * 512; }
        dst = BtAll + (size_t)z * 512 * 1024;
    }
    int n0 = blockIdx.x * 32;
    if (n0 >= cols) return;
    int k0 = blockIdx.y * 32;
    int t = threadIdx.x;
    int r = t >> 3;
    int c4 = (t & 7) * 4;
    float4 v = *(const float4*)&src[srcOff + (size_t)(k0 + r) * srcLd + n0 + c4];
    tl[r][c4 + 0] = f2bf(v.x); tl[r][c4 + 1] = f2bf(v.y);
    tl[r][c4 + 2] = f2bf(v.z); tl[r][c4 + 3] = f2bf(v.w);
    __syncthreads();
    ushort4 o;
    o.x = tl[c4 + 0][r]; o.y = tl[c4 + 1][r]; o.z = tl[c4 + 2][r]; o.w = tl[c4 + 3][r];
    *(ushort4*)&dst[(size_t)(n0 + r) * 1024 + k0 + c4] = o;
}

// ---------------------------------------------------------------------------
// Row-bias precompute (fp32 out):
//  E_op[b][n]  = op_embed[op[b]] . ctx_w[1024+q][n]
//  P_pt[v][n]  = pt_embed[v]     . ctx_w[1280+q][n]
//  dbias[p][h] = dig_b1[p][h] + pos_embed[p] . dig_w1[p][1024+q][h]
// ---------------------------------------------------------------------------
__global__ __launch_bounds__(256) void precompute_bias(
    const float* __restrict__ ctx_w, const float* __restrict__ dig_w1,
    const float* __restrict__ op_embed, const float* __restrict__ pt_embed,
    const float* __restrict__ pos_embed, const float* __restrict__ dig_b1,
    const int* __restrict__ op_type,
    float* __restrict__ E_op, float* __restrict__ P_pt, float* __restrict__ dbias)
{
    int idx = blockIdx.x * 256 + threadIdx.x;
    if (idx < 8192) {
        int b = idx >> 10, n = idx & 1023;
        const float* e = op_embed + op_type[b] * 256;
        float s = 0.f;
        for (int q = 0; q < 256; ++q)
            s += e[q] * ctx_w[(size_t)(1024 + q) * 1024 + n];
        E_op[idx] = s;
    } else if (idx < 18432) {
        int i = idx - 8192;
        int v = i >> 10, n = i & 1023;
        const float* e = pt_embed + v * 256;
        float s = 0.f;
        for (int q = 0; q < 256; ++q)
            s += e[q] * ctx_w[(size_t)(1280 + q) * 1024 + n];
        P_pt[i] = s;
    } else if (idx < 21504) {
        int i = idx - 18432;
        int p = i >> 9, h = i & 511;
        const float* e = pos_embed + p * 256;
        float s = dig_b1[p * 512 + h];
        for (int q = 0; q < 256; ++q)
            s += e[q] * dig_w1[(size_t)p * 1280 * 512 + (size_t)(1024 + q) * 512 + h];
        dbias[i] = s;
    }
}

// ---------------------------------------------------------------------------
// Head GEMM (pure bf16, m97 structure): C[M,N] = A[M,K] @ Bt[N,K]^T.
// 128x128 tile, BK=32, 4 waves 2x2, 4x4 accs, global_load_lds width=16.
// ---------------------------------------------------------------------------
__global__ __launch_bounds__(256) void gemm_bf16(
    const u16* __restrict__ A, const u16* __restrict__ Bt, u16* __restrict__ C,
    int M, int N, int K)
{
    __shared__ u16 As[128 * 32];
    __shared__ u16 Bs[128 * 32];
    const int tid = threadIdx.x;
    const int wid = tid >> 6, lane = tid & 63;
    const int m0 = blockIdx.x * 128, n0 = blockIdx.y * 128;
    const int mw = (wid >> 1) * 64, nw = (wid & 1) * 64;
    const int quad = lane >> 4, r16 = lane & 15;

    f32x4 acc[4][4] = {};

    const int srow = wid * 32 + (lane >> 2);   // wave's 32-row slab, rows 0..15 (+16 2nd call)
    const int scol = (lane & 3) * 8;           // 16B k-chunk
    const u16* gA = A + (size_t)(m0 + srow) * K + scol;
    const u16* gB = Bt + (size_t)(n0 + srow) * K + scol;
    u16* lA = As + wid * 32 * 32;              // wave-uniform LDS base; HW adds lane*16B
    u16* lB = Bs + wid * 32 * 32;

    for (int k0 = 0; k0 < K; k0 += 32) {
        async_load16(gA + k0, lA);
        async_load16(gA + k0 + (size_t)16 * K, lA + 16 * 32);
        async_load16(gB + k0, lB);
        async_load16(gB + k0 + (size_t)16 * K, lB + 16 * 32);
        __syncthreads();   // vmcnt(0) drain: staging visible to all waves
        bf16x8 af[4], bw[4];
#pragma unroll
        for (int i = 0; i < 4; ++i)
            af[i] = *(const bf16x8*)&As[(mw + i * 16 + r16) * 32 + quad * 8];
#pragma unroll
        for (int j = 0; j < 4; ++j)
            bw[j] = *(const bf16x8*)&Bs[(nw + j * 16 + r16) * 32 + quad * 8];
#pragma unroll
        for (int i = 0; i < 4; ++i)
#pragma unroll
            for (int j = 0; j < 4; ++j)
                acc[i][j] = __builtin_amdgcn_mfma_f32_16x16x32_bf16(
                    af[i], bw[j], acc[i][j], 0, 0, 0);
        __syncthreads();   // all ds_reads done before next iter's DMA lands
    }

    // C/D layout: col = lane&15, row = (lane>>4)*4 + reg
#pragma unroll
    for (int i = 0; i < 4; ++i) {
#pragma unroll
        for (int j = 0; j < 4; ++j) {
            int col = n0 + nw + j * 16 + r16;
            size_t base = (size_t)(m0 + mw + i * 16 + quad * 4) * N + col;
#pragma unroll
            for (int r = 0; r < 4; ++r)
                C[base + (size_t)r * N] = f2bf(acc[i][j][r]);
        }
    }
}

// ---------------------------------------------------------------------------
// ctx GEMM: A fp32 (converted in-register), B bf16 async-staged.
// ---------------------------------------------------------------------------
__global__ __launch_bounds__(256) void gemm_f32a(
    const float* __restrict__ A, const u16* __restrict__ Bt, u16* __restrict__ C,
    int M, int N, int K)
{
    __shared__ u16 As[128 * 32];
    __shared__ u16 Bs[128 * 32];
    const int tid = threadIdx.x;
    const int wid = tid >> 6, lane = tid & 63;
    const int m0 = blockIdx.x * 128, n0 = blockIdx.y * 128;
    const int mw = (wid >> 1) * 64, nw = (wid & 1) * 64;
    const int quad = lane >> 4, r16 = lane & 15;

    f32x4 acc[4][4] = {};

    const int srow = wid * 32 + (lane >> 2);
    const int scol = (lane & 3) * 8;
    const u16* gB = Bt + (size_t)(n0 + srow) * K + scol;
    u16* lB = Bs + wid * 32 * 32;

    const int r0 = tid >> 2;          // A staging: rows r0, r0+64
    const int c8 = (tid & 3) * 8;

    for (int k0 = 0; k0 < K; k0 += 32) {
        async_load16(gB + k0, lB);
        async_load16(gB + k0 + (size_t)16 * K, lB + 16 * 32);
        const float* p0 = &A[(size_t)(m0 + r0) * K + k0 + c8];
        const float* p1 = &A[(size_t)(m0 + 64 + r0) * K + k0 + c8];
        float4 x = *(const float4*)p0, y = *(const float4*)(p0 + 4);
        float4 u = *(const float4*)p1, w = *(const float4*)(p1 + 4);
        uint4 a0, a1;
        a0.x = f2bf(x.x) | ((unsigned)f2bf(x.y) << 16);
        a0.y = f2bf(x.z) | ((unsigned)f2bf(x.w) << 16);
        a0.z = f2bf(y.x) | ((unsigned)f2bf(y.y) << 16);
        a0.w = f2bf(y.z) | ((unsigned)f2bf(y.w) << 16);
        a1.x = f2bf(u.x) | ((unsigned)f2bf(u.y) << 16);
        a1.y = f2bf(u.z) | ((unsigned)f2bf(u.w) << 16);
        a1.z = f2bf(w.x) | ((unsigned)f2bf(w.y) << 16);
        a1.w = f2bf(w.z) | ((unsigned)f2bf(w.w) << 16);
        *(uint4*)&As[r0 * 32 + c8] = a0;           // prev-iter readers done (trailing barrier)
        *(uint4*)&As[(64 + r0) * 32 + c8] = a1;
        __syncthreads();   // drains vmcnt (B DMA) + lgkm (A stores)

        bf16x8 af[4], bw[4];
#pragma unroll
        for (int i = 0; i < 4; ++i)
            af[i] = *(const bf16x8*)&As[(mw + i * 16 + r16) * 32 + quad * 8];
#pragma unroll
        for (int j = 0; j < 4; ++j)
            bw[j] = *(const bf16x8*)&Bs[(nw + j * 16 + r16) * 32 + quad * 8];
#pragma unroll
        for (int i = 0; i < 4; ++i)
#pragma unroll
            for (int j = 0; j < 4; ++j)
                acc[i][j] = __builtin_amdgcn_mfma_f32_16x16x32_bf16(
                    af[i], bw[j], acc[i][j], 0, 0, 0);
        __syncthreads();
    }

#pragma unroll
    for (int i = 0; i < 4; ++i) {
#pragma unroll
        for (int j = 0; j < 4; ++j) {
            int col = n0 + nw + j * 16 + r16;
            size_t base = (size_t)(m0 + mw + i * 16 + quad * 4) * N + col;
#pragma unroll
            for (int r = 0; r < 4; ++r)
                C[base + (size_t)r * N] = f2bf(acc[i][j][r]);
        }
    }
}

// ---------------------------------------------------------------------------
// ctx LN+GELU: context = gelu(LN(ctx_pre + E_op[b] + P_pt[pt] + ctx_b))
// ---------------------------------------------------------------------------
__global__ __launch_bounds__(256) void ln_ctx_kernel(
    const u16* __restrict__ pre, const float* __restrict__ E_op,
    const float* __restrict__ P_pt, const int* __restrict__ ptype,
    const u16* __restrict__ csm, u16* __restrict__ ctx, int tokOff)
{
    __shared__ float red[8];
    int local = blockIdx.x;
    int token = tokOff + local;
    int b = token >> 11;            // T = 2048
    int pt = ptype[token];
    int tid = threadIdx.x;
    int c = tid * 4;
    int wid = tid >> 6, lane = tid & 63;

    ushort4 xp = *(const ushort4*)&pre[(size_t)local * 1024 + c];
    float4 eo = *(const float4*)&E_op[b * 1024 + c];
    float4 pp = *(const float4*)&P_pt[pt * 1024 + c];
    ushort4 cb4 = *(const ushort4*)&csm[CTX_B + c];
    float x[4];
    x[0] = bf2f(xp.x) + eo.x + pp.x + bf2f(cb4.x);
    x[1] = bf2f(xp.y) + eo.y + pp.y + bf2f(cb4.y);
    x[2] = bf2f(xp.z) + eo.z + pp.z + bf2f(cb4.z);
    x[3] = bf2f(xp.w) + eo.w + pp.w + bf2f(cb4.w);

    float s = x[0] + x[1] + x[2] + x[3];
    float s2 = x[0]*x[0] + x[1]*x[1] + x[2]*x[2] + x[3]*x[3];
    for (int off = 32; off; off >>= 1) { s += __shfl_xor(s, off); s2 += __shfl_xor(s2, off); }
    if (lane == 0) { red[wid] = s; red[4 + wid] = s2; }
    __syncthreads();
    s  = red[0] + red[1] + red[2] + red[3];
    s2 = red[4] + red[5] + red[6] + red[7];
    float mean = s * (1.f / 1024.f);
    float var = fmaxf(s2 * (1.f / 1024.f) - mean * mean, 0.f);
    float rs = rsqrtf(var + 1e-5f);

    ushort4 g4 = *(const ushort4*)&csm[CTX_G + c];
    ushort4 b4 = *(const ushort4*)&csm[CTX_BE + c];
    ushort4 o;
    o.x = f2bf(gelu_f((x[0] - mean) * rs * bf2f(g4.x) + bf2f(b4.x)));
    o.y = f2bf(gelu_f((x[1] - mean) * rs * bf2f(g4.y) + bf2f(b4.y)));
    o.z = f2bf(gelu_f((x[2] - mean) * rs * bf2f(g4.z) + bf2f(b4.z)));
    o.w = f2bf(gelu_f((x[3] - mean) * rs * bf2f(g4.w) + bf2f(b4.w)));
    *(ushort4*)&ctx[(size_t)token * 1024 + c] = o;
}

// ---------------------------------------------------------------------------
// Unified head finish. Grid (chunk/4, 8). One wave per token per role.
// role 0: sign (cols 0..511), 1..6: digit p=role-1 (cols 1024+p*512),
// role 7: aux (cols 512..1023). fp32 outputs.
// ---------------------------------------------------------------------------
__global__ __launch_bounds__(256) void head_finish(
    const u16* __restrict__ pre, const float* __restrict__ dbias,
    const u16* __restrict__ csm, const float* __restrict__ dw2,
    float* __restrict__ out, int tokOff)
{
    __shared__ u16 w2s[5120];
    int role = blockIdx.y;
    if (role >= 1 && role <= 6) {
        int p = role - 1;
        for (int i = threadIdx.x; i < 5120; i += 256)
            w2s[i] = f2bf(dw2[p * 5120 + i]);
    }
    __syncthreads();

    int wid = threadIdx.x >> 6, lane = threadIdx.x & 63;
    int local = blockIdx.x * 4 + wid;
    int token = tokOff + local;
    int c = lane * 8;

    if (role == 0) {
        // ---- sign: LN(512)+GELU, @sign_w2[512,3]+b2
        const u16* row = pre + (size_t)local * 4096 + c;
        ushort4 a = ((const ushort4*)row)[0];
        ushort4 bq = ((const ushort4*)row)[1];
        u16 xr[8] = {a.x, a.y, a.z, a.w, bq.x, bq.y, bq.z, bq.w};
        float x[8], s = 0.f, s2 = 0.f;
#pragma unroll
        for (int j = 0; j < 8; ++j) {
            x[j] = bf2f(xr[j]) + bf2f(csm[S_B1 + c + j]);
            s += x[j]; s2 += x[j] * x[j];
        }
        for (int off = 32; off; off >>= 1) { s += __shfl_xor(s, off); s2 += __shfl_xor(s2, off); }
        float mean = s * (1.f / 512.f);
        float var = fmaxf(s2 * (1.f / 512.f) - mean * mean, 0.f);
        float rs = rsqrtf(var + 1e-5f);
        float p0 = 0.f, p1 = 0.f, p2 = 0.f;
#pragma unroll
        for (int j = 0; j < 8; ++j) {
            float g = gelu_f((x[j] - mean) * rs * bf2f(csm[S_G + c + j]) + bf2f(csm[S_BE + c + j]));
            p0 += g * bf2f(csm[S_W2 + (c + j) * 3 + 0]);
            p1 += g * bf2f(csm[S_W2 + (c + j) * 3 + 1]);
            p2 += g * bf2f(csm[S_W2 + (c + j) * 3 + 2]);
        }
        for (int off = 32; off; off >>= 1) {
            p0 += __shfl_xor(p0, off); p1 += __shfl_xor(p1, off); p2 += __shfl_xor(p2, off);
        }
        if (lane == 0) {
            out[(size_t)token * 3 + 0] = p0 + bf2f(csm[S_B2 + 0]);
            out[(size_t)token * 3 + 1] = p1 + bf2f(csm[S_B2 + 1]);
            out[(size_t)token * 3 + 2] = p2 + bf2f(csm[S_B2 + 2]);
        }
    } else if (role == 7) {
        // ---- aux: gelu(pre + b1) . aux_w2 + b2
        const u16* row = pre + (size_t)local * 4096 + 512 + c;
        ushort4 a = ((const ushort4*)row)[0];
        ushort4 bq = ((const ushort4*)row)[1];
        u16 xr[8] = {a.x, a.y, a.z, a.w, bq.x, bq.y, bq.z, bq.w};
        float s = 0.f;
#pragma unroll
        for (int j = 0; j < 8; ++j) {
            float xv = bf2f(xr[j]) + bf2f(csm[A_B1 + c + j]);
            s += gelu_f(xv) * bf2f(csm[A_W2 + c + j]);
        }
        for (int off = 32; off; off >>= 1) s += __shfl_xor(s, off);
        if (lane == 0) out[1032192 + (size_t)token] = s + bf2f(csm[A_B2]);
    } else {
        // ---- digit p: LN(512)+GELU (bias incl pos term) then @dig_w2[p]+b2
        int p = role - 1;
        const u16* row = pre + (size_t)local * 4096 + 1024 + p * 512 + c;
        ushort4 a = ((const ushort4*)row)[0];
        ushort4 bq = ((const ushort4*)row)[1];
        u16 xr[8] = {a.x, a.y, a.z, a.w, bq.x, bq.y, bq.z, bq.w};
        int cb = p * 512 + c;
        float4 d0 = *(const float4*)&dbias[cb];
        float4 d1 = *(const float4*)&dbias[cb + 4];
        float db[8] = {d0.x, d0.y, d0.z, d0.w, d1.x, d1.y, d1.z, d1.w};
        float x[8], s = 0.f, s2 = 0.f;
#pragma unroll
        for (int j = 0; j < 8; ++j) {
            x[j] = bf2f(xr[j]) + db[j];
            s += x[j]; s2 += x[j] * x[j];
        }
        for (int off = 32; off; off >>= 1) { s += __shfl_xor(s, off); s2 += __shfl_xor(s2, off); }
        float mean = s * (1.f / 512.f);
        float var = fmaxf(s2 * (1.f / 512.f) - mean * mean, 0.f);
        float rs = rsqrtf(var + 1e-5f);
        float pt[10] = {};
#pragma unroll
        for (int j = 0; j < 8; ++j) {
            float gv = gelu_f((x[j] - mean) * rs * bf2f(csm[D_G + cb + j]) + bf2f(csm[D_BE + cb + j]));
            int wrow = (c + j) * 10;
#pragma unroll
            for (int o = 0; o < 10; ++o) pt[o] += gv * bf2f(w2s[wrow + o]);
        }
#pragma unroll
        for (int o = 0; o < 10; ++o)
            for (int off = 32; off; off >>= 1) pt[o] += __shfl_xor(pt[o], off);
        if (lane < 10)
            out[49152 + ((size_t)token * 6 + p) * 10 + lane] = pt[lane] + bf2f(csm[D_B2 + p * 10 + lane]);
    }
}

// ---------------------------------------------------------------------------
extern "C" void kernel_launch(void* const* d_in, const int* in_sizes, int n_in,
                              void* d_out, int out_size, void* d_ws, size_t ws_size,
                              hipStream_t stream) {
    const float* hidden    = (const float*)d_in[0];
    const int*   op_type   = (const int*)d_in[1];
    const int*   pt_type   = (const int*)d_in[2];
    const float* op_embed  = (const float*)d_in[3];
    const float* pt_embed  = (const float*)d_in[4];
    const float* pos_embed = (const float*)d_in[5];
    const float* ctx_w     = (const float*)d_in[6];
    const float* sign_w1   = (const float*)d_in[10];
    const float* dig_w1    = (const float*)d_in[16];
    const float* dig_b1    = (const float*)d_in[17];
    const float* dig_w2    = (const float*)d_in[20];
    const float* aux_w1    = (const float*)d_in[22];

    char* ws = (char*)d_ws;
    // fixed ws layout (bytes):
    u16*   ctxWt   = (u16*)(ws + 0);           //  2,097,152
    u16*   BtAll   = (u16*)(ws + 2097152);     //  8,388,608  [4096,1024]
    float* E_op    = (float*)(ws + 10485760);  //     32,768
    float* P_pt    = (float*)(ws + 10518528);  //     40,960
    float* dbias   = (float*)(ws + 10559488);  //     12,288
    u16*   csm     = (u16*)(ws + 10571776);    //     65,536  canonical small vecs
    u16*   context = (u16*)(ws + 10637312);    // 33,554,432  [16384,1024]
    u16*   scratch = (u16*)(ws + 44191744);    // remainder
    size_t S = (ws_size > 44191744) ? ws_size - 44191744 : 0;

    // adapt chunk sizes to available scratch (known lower bound: 61 MB total ws)
    int Rc = 16384;                                   // ctx chunk rows (needs Rc*2048 B)
    while ((size_t)Rc * 2048 > S && Rc > 128) Rc >>= 1;
    int Rh = 16384;                                   // head chunk rows (needs Rh*8192 B)
    while ((size_t)Rh * 8192 > S && Rh > 128) Rh >>= 1;

    float* out = (float*)d_out;

    SmallTab tab;
    const float* srcs[17] = { op_embed, pt_embed, pos_embed,
                              (const float*)d_in[7], (const float*)d_in[8], (const float*)d_in[9],
                              (const float*)d_in[11], (const float*)d_in[12], (const float*)d_in[13],
                              (const float*)d_in[14], (const float*)d_in[15],
                              (const float*)d_in[18], (const float*)d_in[19], (const float*)d_in[21],
                              (const float*)d_in[23], (const float*)d_in[24], (const float*)d_in[25] };
    const int offs[17] = { OP_E, PT_E, POS_E, CTX_B, CTX_G, CTX_BE,
                           S_B1, S_G, S_BE, S_W2, S_B2,
                           D_G, D_BE, D_B2, A_B1, A_W2, A_B2 };
    const int cnts[17] = { 2304, 2560, 1536, 1024, 1024, 1024,
                           512, 512, 512, 1536, 3,
                           3072, 3072, 60, 512, 512, 1 };
    for (int i = 0; i < 17; ++i) { tab.src[i] = srcs[i]; tab.off[i] = offs[i]; tab.cnt[i] = cnts[i]; }
    convert_small<<<78, 256, 0, stream>>>(tab, csm);

    transpose_all<<<dim3(32, 32, 9), 256, 0, stream>>>(
        ctx_w, sign_w1, aux_w1, dig_w1, ctxWt, BtAll);
    precompute_bias<<<84, 256, 0, stream>>>(
        ctx_w, dig_w1, op_embed, pt_embed, pos_embed, dig_b1, op_type,
        E_op, P_pt, dbias);

    // context = gelu(LN(hidden @ ctx_w[:1024] + E_op + P_pt + b))
    for (int t0 = 0; t0 < 16384; t0 += Rc) {
        gemm_f32a<<<dim3(Rc / 128, 8), 256, 0, stream>>>(
            hidden + (size_t)t0 * 1024, ctxWt, scratch, Rc, 1024, 1024);
        ln_ctx_kernel<<<Rc, 256, 0, stream>>>(
            scratch, E_op, P_pt, pt_type, csm, context, t0);
    }

    // head_pre = context @ BtAll^T ; then fused finishes
    for (int t0 = 0; t0 < 16384; t0 += Rh) {
        gemm_bf16<<<dim3(Rh / 128, 32), 256, 0, stream>>>(
            context + (size_t)t0 * 1024, BtAll, scratch, Rh, 4096, 1024);
        head_finish<<<dim3(Rh / 4, 8), 256, 0, stream>>>(
            scratch, dbias, csm, dig_w2, out, t0);
    }
}